// Round 4
// baseline (446.839 us; speedup 1.0000x reference)
//
#include <hip/hip_runtime.h>
#include <hip/hip_bf16.h>
#include <stdint.h>

#define SEQ    2048
#define HIDDEN 1024
#define NH     16
#define HD     64

typedef __bf16 bf16x8 __attribute__((ext_vector_type(8)));
typedef float  f32x4  __attribute__((ext_vector_type(4)));

typedef __attribute__((address_space(1))) void* as1vp;
typedef __attribute__((address_space(3))) void* as3vp;

__device__ __forceinline__ void gload_lds16(const void* g, void* l) {
  // global -> LDS direct copy, 16B/lane. LDS dest = wave-uniform base + lane*16.
  __builtin_amdgcn_global_load_lds((as1vp)(void*)g, (as3vp)l, 16, 0, 0);
}

__device__ __forceinline__ uint16_t f2bf(float f) {
  uint32_t x;
  __builtin_memcpy(&x, &f, 4);
  x += 0x7FFFu + ((x >> 16) & 1u);   // round-to-nearest-even
  return (uint16_t)(x >> 16);
}

// ---------------------------------------------------------------------------
// Convert Q/K/V fp32 -> bf16 (tensor selected by blockIdx.y).
// ---------------------------------------------------------------------------
__global__ __launch_bounds__(256) void k_cvt(
    const float* __restrict__ Q, const float* __restrict__ K, const float* __restrict__ V,
    uint16_t* __restrict__ Qb, uint16_t* __restrict__ Kb, uint16_t* __restrict__ Vb) {
  const float* src = (blockIdx.y == 0) ? Q : (blockIdx.y == 1) ? K : V;
  uint16_t*    dst = (blockIdx.y == 0) ? Qb : (blockIdx.y == 1) ? Kb : Vb;
  const int i = (blockIdx.x * 256 + threadIdx.x) * 8;
  float4 v0 = *(const float4*)(src + i);
  float4 v1 = *(const float4*)(src + i + 4);
  uint16_t tmp[8];
  tmp[0] = f2bf(v0.x); tmp[1] = f2bf(v0.y); tmp[2] = f2bf(v0.z); tmp[3] = f2bf(v0.w);
  tmp[4] = f2bf(v1.x); tmp[5] = f2bf(v1.y); tmp[6] = f2bf(v1.z); tmp[7] = f2bf(v1.w);
  __builtin_memcpy(dst + i, tmp, 16);
}

// ---------------------------------------------------------------------------
// Transpose W fp32 [K=1024][N=1024] -> WT bf16 [N][K] (matrix by blockIdx.y)
// ---------------------------------------------------------------------------
__global__ __launch_bounds__(256) void k_transpose(
    const float* __restrict__ W0, const float* __restrict__ W1, const float* __restrict__ W2,
    uint16_t* __restrict__ T0, uint16_t* __restrict__ T1, uint16_t* __restrict__ T2) {
  __shared__ uint16_t t[64][65];
  const float* W = (blockIdx.y == 0) ? W0 : (blockIdx.y == 1) ? W1 : W2;
  uint16_t*    T = (blockIdx.y == 0) ? T0 : (blockIdx.y == 1) ? T1 : T2;
  const int bx = blockIdx.x & 15, by = blockIdx.x >> 4;
  const int tx = threadIdx.x & 63, ty = threadIdx.x >> 6;
  for (int i = ty; i < 64; i += 4)
    t[i][tx] = f2bf(W[(by * 64 + i) * HIDDEN + bx * 64 + tx]);
  __syncthreads();
  for (int i = ty; i < 64; i += 4)
    T[(bx * 64 + i) * HIDDEN + by * 64 + tx] = t[tx][i];
}

// ---------------------------------------------------------------------------
// QKV projection GEMM: out = X @ W + b  (B^T layout via WT, bf16 in / bf16 out)
// 128x128 tile, BK=64, 4 waves each 64x64, mfma_f32_16x16x32_bf16. Linear LDS.
// mode (blockIdx.z): 0=q (scaled 0.125, [b,h,s,d]) 1=k ([b,h,s,d]) 2=v ([b,h,d,s])
// ---------------------------------------------------------------------------
__global__ __launch_bounds__(256) void k_qkv_gemm(
    const uint16_t* __restrict__ Qb, const uint16_t* __restrict__ Kb, const uint16_t* __restrict__ Vb,
    const uint16_t* __restrict__ WTq, const uint16_t* __restrict__ WTk, const uint16_t* __restrict__ WTv,
    const float* __restrict__ Bq, const float* __restrict__ Bk, const float* __restrict__ Bv,
    uint16_t* __restrict__ q_ws, uint16_t* __restrict__ k_ws, uint16_t* __restrict__ v_ws) {
  const int mode = blockIdx.z;
  const uint16_t* X   = (mode == 0) ? Qb : (mode == 1) ? Kb : Vb;
  const uint16_t* WT  = (mode == 0) ? WTq : (mode == 1) ? WTk : WTv;
  const float*    bia = (mode == 0) ? Bq  : (mode == 1) ? Bk  : Bv;

  __shared__ uint16_t As[128 * 64];
  __shared__ uint16_t Bs[128 * 64];
  char* AsB = (char*)As;
  char* BsB = (char*)Bs;

  const int tid  = threadIdx.x;
  const int lane = tid & 63;
  const int w    = tid >> 6;
  const int wr   = w >> 1, wc = w & 1;
  const int m0   = blockIdx.y * 128;
  const int n0   = blockIdx.x * 128;

  const int lrow = lane >> 3;
  const int lcol = (lane & 7) * 16;

  f32x4 acc[4][4];
  const f32x4 zero = {0.f, 0.f, 0.f, 0.f};
#pragma unroll
  for (int i = 0; i < 4; ++i)
#pragma unroll
    for (int j = 0; j < 4; ++j) acc[i][j] = zero;

  const char* Ab = (const char*)X;
  const char* Bb = (const char*)WT;

  for (int kt = 0; kt < 16; ++kt) {
    __syncthreads();
    const int kbyte = kt * 128;
#pragma unroll
    for (int i = 0; i < 4; ++i) {
      const int r = w * 32 + i * 8;
      gload_lds16(Ab + (size_t)(m0 + r + lrow) * (HIDDEN * 2) + kbyte + lcol, AsB + r * 128);
      gload_lds16(Bb + (size_t)(n0 + r + lrow) * (HIDDEN * 2) + kbyte + lcol, BsB + r * 128);
    }
    __syncthreads();
#pragma unroll
    for (int kc = 0; kc < 2; ++kc) {
      const int chunk = kc * 64 + (lane >> 4) * 16;
      bf16x8 a[4], b[4];
#pragma unroll
      for (int f = 0; f < 4; ++f) {
        const int ra = wr * 64 + f * 16 + (lane & 15);
        a[f] = *(const bf16x8*)(AsB + ra * 128 + chunk);
        const int rb = wc * 64 + f * 16 + (lane & 15);
        b[f] = *(const bf16x8*)(BsB + rb * 128 + chunk);
      }
#pragma unroll
      for (int fm = 0; fm < 4; ++fm)
#pragma unroll
        for (int fn = 0; fn < 4; ++fn)
          acc[fm][fn] = __builtin_amdgcn_mfma_f32_16x16x32_bf16(a[fm], b[fn], acc[fm][fn], 0, 0, 0);
    }
  }

  float bfrag[4];
#pragma unroll
  for (int fn = 0; fn < 4; ++fn)
    bfrag[fn] = bia[n0 + wc * 64 + fn * 16 + (lane & 15)];

#pragma unroll
  for (int fm = 0; fm < 4; ++fm) {
    const int mrow0 = m0 + wr * 64 + fm * 16 + (lane >> 4) * 4;
    const int b0 = mrow0 >> 11;
    const int s0 = mrow0 & (SEQ - 1);
#pragma unroll
    for (int fn = 0; fn < 4; ++fn) {
      const int n = n0 + wc * 64 + fn * 16 + (lane & 15);
      const int h = n >> 6, d = n & 63;
      if (mode == 2) {
        uint16_t tmp[4];
#pragma unroll
        for (int j = 0; j < 4; ++j) tmp[j] = f2bf(acc[fm][fn][j] + bfrag[fn]);
        __builtin_memcpy(v_ws + ((size_t)(b0 * NH + h) * HD + d) * SEQ + s0, tmp, 8);
      } else {
        const float sc = (mode == 0) ? 0.125f : 1.0f;
        uint16_t* o = (mode == 0) ? q_ws : k_ws;
#pragma unroll
        for (int j = 0; j < 4; ++j)
          o[((size_t)(b0 * NH + h) * SEQ + (s0 + j)) * HD + d] =
              f2bf((acc[fm][fn][j] + bfrag[fn]) * sc);
      }
    }
  }
}

// ---------------------------------------------------------------------------
// Flash attention: grid (32 q-tiles, 32 bh), 4 waves x 16 q-rows, KV tile = 64.
// Latency-optimized: K register ping-pong prefetch, early V issue, deferred
// l-reduction, defer-max rescale skip (THR=5).
// ---------------------------------------------------------------------------
__global__ __launch_bounds__(256, 4) void k_attn(
    const uint16_t* __restrict__ q_ws, const uint16_t* __restrict__ k_ws,
    const uint16_t* __restrict__ v_ws, const float* __restrict__ mask,
    float* __restrict__ out) {
  __shared__ uint16_t Pt[4][16 * 64];   // per-wave P (bf16), swizzled rows

  const int tid = threadIdx.x, lane = tid & 63, w = tid >> 6;
  const int bh = blockIdx.y;
  const int b  = bh >> 4;
  const int h  = bh & 15;
  const int q0 = blockIdx.x * 64 + w * 16;

  char* PtB = (char*)(&Pt[w][0]);
  const char* kb = (const char*)k_ws;
  const char* vb = (const char*)v_ws;

  // Q fragments in registers for the whole kernel
  bf16x8 qf0, qf1;
  {
    const char* qb = (const char*)q_ws;
    const size_t rowb = ((size_t)bh * SEQ + q0 + (lane & 15)) * (HD * 2);
    qf0 = *(const bf16x8*)(qb + rowb + (lane >> 4) * 16);
    qf1 = *(const bf16x8*)(qb + rowb + 64 + (lane >> 4) * 16);
  }

  const f32x4 zero = {0.f, 0.f, 0.f, 0.f};
  f32x4 Oacc[4];
#pragma unroll
  for (int i = 0; i < 4; ++i) Oacc[i] = zero;
  float mrun[4], lpart[4];
#pragma unroll
  for (int j = 0; j < 4; ++j) { mrun[j] = -1e30f; lpart[j] = 0.f; }

  // K fragments for one 64-key tile: kf[2g] = first 32 d, kf[2g+1] = last 32 d
  auto loadK = [&](int kt, bf16x8 (&kf)[8]) {
#pragma unroll
    for (int g = 0; g < 4; ++g) {
      const char* kr = kb + ((size_t)bh * SEQ + kt * 64 + g * 16 + (lane & 15)) * (HD * 2)
                       + (lane >> 4) * 16;
      kf[2 * g]     = *(const bf16x8*)(kr);
      kf[2 * g + 1] = *(const bf16x8*)(kr + 64);
    }
  };

  bf16x8 kA[8], kB[8];
  loadK(0, kA);

  auto body = [&](int kt, bf16x8 (&kf)[8], bf16x8 (&kn)[8]) {
    // ---- early V issue (consumed at the end of this iteration) ----
    bf16x8 vf[8];
#pragma unroll
    for (int dg = 0; dg < 4; ++dg) {
      const char* vr = vb + ((size_t)bh * HD + dg * 16 + (lane & 15)) * (SEQ * 2)
                       + kt * 128 + (lane >> 4) * 16;
      vf[dg]     = *(const bf16x8*)(vr);       // keys kt*64 .. +31
      vf[4 + dg] = *(const bf16x8*)(vr + 64);  // keys kt*64+32 .. +63
    }
    float mv[4];
#pragma unroll
    for (int g = 0; g < 4; ++g)
      mv[g] = mask[b * SEQ + kt * 64 + g * 16 + (lane & 15)] * 0.125f;

    // ---- QK^T on resident K ----
    f32x4 sv[4];
#pragma unroll
    for (int g = 0; g < 4; ++g) {
      f32x4 t = __builtin_amdgcn_mfma_f32_16x16x32_bf16(qf0, kf[2 * g], zero, 0, 0, 0);
      sv[g]   = __builtin_amdgcn_mfma_f32_16x16x32_bf16(qf1, kf[2 * g + 1], t, 0, 0, 0);
    }

    // ---- prefetch next tile's K (latency hidden under softmax+PV) ----
    const int ktn = (kt + 1 < 32) ? kt + 1 : 31;
    loadK(ktn, kn);

#pragma unroll
    for (int g = 0; g < 4; ++g)
#pragma unroll
      for (int j = 0; j < 4; ++j) sv[g][j] += mv[g];

    // ---- tile max per q-row (4 shuffles across the 16-lane group) ----
    float pmax[4];
#pragma unroll
    for (int j = 0; j < 4; ++j) {
      float v = fmaxf(fmaxf(sv[0][j], sv[1][j]), fmaxf(sv[2][j], sv[3][j]));
#pragma unroll
      for (int mk = 1; mk < 16; mk <<= 1) v = fmaxf(v, __shfl_xor(v, mk, 64));
      pmax[j] = v;
    }

    // ---- defer-max: skip rescale unless the max grew by more than THR ----
    bool ok = (pmax[0] - mrun[0] <= 5.f) && (pmax[1] - mrun[1] <= 5.f) &&
              (pmax[2] - mrun[2] <= 5.f) && (pmax[3] - mrun[3] <= 5.f);
    if (!__all(ok)) {
#pragma unroll
      for (int j = 0; j < 4; ++j) {
        const float mnew = fmaxf(mrun[j], pmax[j]);
        const float esc  = __expf(mrun[j] - mnew);
        mrun[j]  = mnew;
        lpart[j] *= esc;
#pragma unroll
        for (int dg = 0; dg < 4; ++dg) Oacc[dg][j] *= esc;
      }
    }

    // ---- exp + per-lane partial l (cross-lane sum deferred to the end) ----
#pragma unroll
    for (int j = 0; j < 4; ++j) {
      float s = 0.f;
#pragma unroll
      for (int g = 0; g < 4; ++g) {
        const float p = __expf(sv[g][j] - mrun[j]);
        sv[g][j] = p;
        s += p;
      }
      lpart[j] += s;
    }

    // ---- P -> per-wave LDS (C-layout -> A-fragment layout), swizzled ----
#pragma unroll
    for (int g = 0; g < 4; ++g)
#pragma unroll
      for (int j = 0; j < 4; ++j) {
        const int row = (lane >> 4) * 4 + j;
        const int col = g * 16 + (lane & 15);
        ((__bf16*)PtB)[row * 64 + (col ^ ((row & 7) << 3))] = (__bf16)sv[g][j];
      }

    // ---- PV with early-issued V fragments ----
#pragma unroll
    for (int kc = 0; kc < 2; ++kc) {
      const int chunk = kc * 64 + (lane >> 4) * 16;
      const int pr = lane & 15;
      bf16x8 pa = *(const bf16x8*)(PtB + pr * 128 + (chunk ^ ((pr & 7) << 4)));
#pragma unroll
      for (int dg = 0; dg < 4; ++dg)
        Oacc[dg] = __builtin_amdgcn_mfma_f32_16x16x32_bf16(pa, vf[kc * 4 + dg], Oacc[dg], 0, 0, 0);
    }
  };

  for (int kt = 0; kt < 32; kt += 2) {
    body(kt,     kA, kB);
    body(kt + 1, kB, kA);
  }

  // ---- final cross-lane l reduction (once) ----
  float lrun[4];
#pragma unroll
  for (int j = 0; j < 4; ++j) {
    float v = lpart[j];
#pragma unroll
    for (int mk = 1; mk < 16; mk <<= 1) v += __shfl_xor(v, mk, 64);
    lrun[j] = v;
  }

  // epilogue: normalize and write out[b, q, h*64+d] (fp32)
#pragma unroll
  for (int dg = 0; dg < 4; ++dg)
#pragma unroll
    for (int j = 0; j < 4; ++j) {
      const int q = q0 + (lane >> 4) * 4 + j;
      const int d = dg * 16 + (lane & 15);
      out[(size_t)(b * SEQ + q) * HIDDEN + h * HD + d] = Oacc[dg][j] / lrun[j];
    }
}

// ---------------------------------------------------------------------------
extern "C" void kernel_launch(void* const* d_in, const int* in_sizes, int n_in,
                              void* d_out, int out_size, void* d_ws, size_t ws_size,
                              hipStream_t stream) {
  (void)in_sizes; (void)n_in; (void)out_size; (void)ws_size;
  const float* Q    = (const float*)d_in[0];
  const float* K    = (const float*)d_in[1];
  const float* V    = (const float*)d_in[2];
  const float* mask = (const float*)d_in[3];
  const float* Wq   = (const float*)d_in[4];
  const float* bq   = (const float*)d_in[5];
  const float* Wk   = (const float*)d_in[6];
  const float* bk   = (const float*)d_in[7];
  const float* Wv   = (const float*)d_in[8];
  const float* bv   = (const float*)d_in[9];

  uint16_t* ws   = (uint16_t*)d_ws;
  uint16_t* wt_q = ws;
  uint16_t* wt_k = wt_q + HIDDEN * HIDDEN;
  uint16_t* wt_v = wt_k + HIDDEN * HIDDEN;
  const size_t qkv = (size_t)2 * SEQ * HIDDEN;
  uint16_t* Qb   = wt_v + HIDDEN * HIDDEN;
  uint16_t* Kb   = Qb + qkv;
  uint16_t* Vb   = Kb + qkv;
  uint16_t* q_ws = Vb + qkv;
  uint16_t* k_ws = q_ws + qkv;
  uint16_t* v_ws = k_ws + qkv;

  k_cvt<<<dim3(2048, 3), 256, 0, stream>>>(Q, K, V, Qb, Kb, Vb);
  k_transpose<<<dim3(256, 3), 256, 0, stream>>>(Wq, Wk, Wv, wt_q, wt_k, wt_v);
  k_qkv_gemm<<<dim3(HIDDEN / 128, (2 * SEQ) / 128, 3), 256, 0, stream>>>(
      Qb, Kb, Vb, wt_q, wt_k, wt_v, bq, bk, bv, q_ws, k_ws, v_ws);
  k_attn<<<dim3(SEQ / 64, 2 * NH), 256, 0, stream>>>(q_ws, k_ws, v_ws, mask,
                                                     (float*)d_out);
}

// Round 6
// 204.795 us; speedup vs baseline: 2.1819x; 2.1819x over previous
//
#include <hip/hip_runtime.h>
#include <hip/hip_bf16.h>
#include <stdint.h>

#define SEQ    2048
#define HIDDEN 1024
#define NH     16
#define HD     64

// log2(e)/8 : folds both the 1/sqrt(64) scale and the exp->exp2 conversion
#define SC_LOG2E_8 0.18033688011112042f

typedef __bf16 bf16x8 __attribute__((ext_vector_type(8)));
typedef float  f32x4  __attribute__((ext_vector_type(4)));
typedef float  f32x16 __attribute__((ext_vector_type(16)));
typedef unsigned int uint32x2 __attribute__((ext_vector_type(2)));

typedef __attribute__((address_space(1))) void* as1vp;
typedef __attribute__((address_space(3))) void* as3vp;

__device__ __forceinline__ void gload_lds16(const void* g, void* l) {
  __builtin_amdgcn_global_load_lds((as1vp)(void*)g, (as3vp)l, 16, 0, 0);
}

__device__ __forceinline__ uint16_t f2bf(float f) {
  uint32_t x;
  __builtin_memcpy(&x, &f, 4);
  x += 0x7FFFu + ((x >> 16) & 1u);   // round-to-nearest-even
  return (uint16_t)(x >> 16);
}

// pack two floats to one u32 of 2 bf16 (lo, hi) -- compiler emits v_cvt_pk
__device__ __forceinline__ uint32_t pkbf(float lo, float hi) {
  union { __bf16 v[2]; uint32_t u; } t;
  t.v[0] = (__bf16)lo; t.v[1] = (__bf16)hi;
  return t.u;
}

// v_permlane32_swap_b32 (builtin): swaps vdst[32:63] <-> vsrc[0:31].
// Returns {vdst', vsrc'}. With (lowWord, highWord) inputs, r[0] is the
// fragment word for the low k-slot and r[1] for the high k-slot (HK pattern).
__device__ __forceinline__ uint32x2 plswap(uint32_t lo, uint32_t hi) {
  return __builtin_amdgcn_permlane32_swap(lo, hi, false, false);
}

// value held by partner lane (lane ^ 32)
__device__ __forceinline__ float xhalf32(float x, int lane) {
  uint32_t a;
  __builtin_memcpy(&a, &x, 4);
  uint32x2 r = plswap(a, a);
  // r[0]: hi lanes hold partner's value; r[1]: lo lanes hold partner's value
  uint32_t p = (lane < 32) ? r[1] : r[0];
  float f;
  __builtin_memcpy(&f, &p, 4);
  return f;
}

__device__ __forceinline__ float exp2_fast(float x) {
  return __builtin_amdgcn_exp2f(x);
}

// ---------------------------------------------------------------------------
// Convert Q/K/V fp32 -> bf16 (tensor selected by blockIdx.y).
// ---------------------------------------------------------------------------
__global__ __launch_bounds__(256) void k_cvt(
    const float* __restrict__ Q, const float* __restrict__ K, const float* __restrict__ V,
    uint16_t* __restrict__ Qb, uint16_t* __restrict__ Kb, uint16_t* __restrict__ Vb) {
  const float* src = (blockIdx.y == 0) ? Q : (blockIdx.y == 1) ? K : V;
  uint16_t*    dst = (blockIdx.y == 0) ? Qb : (blockIdx.y == 1) ? Kb : Vb;
  const int i = (blockIdx.x * 256 + threadIdx.x) * 8;
  float4 v0 = *(const float4*)(src + i);
  float4 v1 = *(const float4*)(src + i + 4);
  uint16_t tmp[8];
  tmp[0] = f2bf(v0.x); tmp[1] = f2bf(v0.y); tmp[2] = f2bf(v0.z); tmp[3] = f2bf(v0.w);
  tmp[4] = f2bf(v1.x); tmp[5] = f2bf(v1.y); tmp[6] = f2bf(v1.z); tmp[7] = f2bf(v1.w);
  __builtin_memcpy(dst + i, tmp, 16);
}

// ---------------------------------------------------------------------------
// Transpose W fp32 [K=1024][N=1024] -> WT bf16 [N][K] (matrix by blockIdx.y)
// ---------------------------------------------------------------------------
__global__ __launch_bounds__(256) void k_transpose(
    const float* __restrict__ W0, const float* __restrict__ W1, const float* __restrict__ W2,
    uint16_t* __restrict__ T0, uint16_t* __restrict__ T1, uint16_t* __restrict__ T2) {
  __shared__ uint16_t t[64][65];
  const float* W = (blockIdx.y == 0) ? W0 : (blockIdx.y == 1) ? W1 : W2;
  uint16_t*    T = (blockIdx.y == 0) ? T0 : (blockIdx.y == 1) ? T1 : T2;
  const int bx = blockIdx.x & 15, by = blockIdx.x >> 4;
  const int tx = threadIdx.x & 63, ty = threadIdx.x >> 6;
  for (int i = ty; i < 64; i += 4)
    t[i][tx] = f2bf(W[(by * 64 + i) * HIDDEN + bx * 64 + tx]);
  __syncthreads();
  for (int i = ty; i < 64; i += 4)
    T[(bx * 64 + i) * HIDDEN + by * 64 + tx] = t[tx][i];
}

// ---------------------------------------------------------------------------
// QKV projection GEMM: out = X @ W + b  (B^T layout via WT, bf16 in / bf16 out)
// 128x128 tile, BK=64, 4 waves each 64x64, mfma_f32_16x16x32_bf16. Linear LDS.
// mode: 0=q (scaled by log2e/8, [b,h,s,d]) 1=k ([b,h,s,d]) 2=v ([b,h,d,s])
// ---------------------------------------------------------------------------
__global__ __launch_bounds__(256) void k_qkv_gemm(
    const uint16_t* __restrict__ Qb, const uint16_t* __restrict__ Kb, const uint16_t* __restrict__ Vb,
    const uint16_t* __restrict__ WTq, const uint16_t* __restrict__ WTk, const uint16_t* __restrict__ WTv,
    const float* __restrict__ Bq, const float* __restrict__ Bk, const float* __restrict__ Bv,
    uint16_t* __restrict__ q_ws, uint16_t* __restrict__ k_ws, uint16_t* __restrict__ v_ws) {
  const int mode = blockIdx.z;
  const uint16_t* X   = (mode == 0) ? Qb : (mode == 1) ? Kb : Vb;
  const uint16_t* WT  = (mode == 0) ? WTq : (mode == 1) ? WTk : WTv;
  const float*    bia = (mode == 0) ? Bq  : (mode == 1) ? Bk  : Bv;

  __shared__ uint16_t As[128 * 64];
  __shared__ uint16_t Bs[128 * 64];
  char* AsB = (char*)As;
  char* BsB = (char*)Bs;

  const int tid  = threadIdx.x;
  const int lane = tid & 63;
  const int w    = tid >> 6;
  const int wr   = w >> 1, wc = w & 1;
  const int m0   = blockIdx.y * 128;
  const int n0   = blockIdx.x * 128;

  const int lrow = lane >> 3;
  const int lcol = (lane & 7) * 16;

  f32x4 acc[4][4];
  const f32x4 zero = {0.f, 0.f, 0.f, 0.f};
#pragma unroll
  for (int i = 0; i < 4; ++i)
#pragma unroll
    for (int j = 0; j < 4; ++j) acc[i][j] = zero;

  const char* Ab = (const char*)X;
  const char* Bb = (const char*)WT;

  for (int kt = 0; kt < 16; ++kt) {
    __syncthreads();
    const int kbyte = kt * 128;
#pragma unroll
    for (int i = 0; i < 4; ++i) {
      const int r = w * 32 + i * 8;
      gload_lds16(Ab + (size_t)(m0 + r + lrow) * (HIDDEN * 2) + kbyte + lcol, AsB + r * 128);
      gload_lds16(Bb + (size_t)(n0 + r + lrow) * (HIDDEN * 2) + kbyte + lcol, BsB + r * 128);
    }
    __syncthreads();
#pragma unroll
    for (int kc = 0; kc < 2; ++kc) {
      const int chunk = kc * 64 + (lane >> 4) * 16;
      bf16x8 a[4], b[4];
#pragma unroll
      for (int f = 0; f < 4; ++f) {
        const int ra = wr * 64 + f * 16 + (lane & 15);
        a[f] = *(const bf16x8*)(AsB + ra * 128 + chunk);
        const int rb = wc * 64 + f * 16 + (lane & 15);
        b[f] = *(const bf16x8*)(BsB + rb * 128 + chunk);
      }
#pragma unroll
      for (int fm = 0; fm < 4; ++fm)
#pragma unroll
        for (int fn = 0; fn < 4; ++fn)
          acc[fm][fn] = __builtin_amdgcn_mfma_f32_16x16x32_bf16(a[fm], b[fn], acc[fm][fn], 0, 0, 0);
    }
  }

  float bfrag[4];
#pragma unroll
  for (int fn = 0; fn < 4; ++fn)
    bfrag[fn] = bia[n0 + wc * 64 + fn * 16 + (lane & 15)];

#pragma unroll
  for (int fm = 0; fm < 4; ++fm) {
    const int mrow0 = m0 + wr * 64 + fm * 16 + (lane >> 4) * 4;
    const int b0 = mrow0 >> 11;
    const int s0 = mrow0 & (SEQ - 1);
#pragma unroll
    for (int fn = 0; fn < 4; ++fn) {
      const int n = n0 + wc * 64 + fn * 16 + (lane & 15);
      const int h = n >> 6, d = n & 63;
      if (mode == 2) {
        uint16_t tmp[4];
#pragma unroll
        for (int j = 0; j < 4; ++j) tmp[j] = f2bf(acc[fm][fn][j] + bfrag[fn]);
        __builtin_memcpy(v_ws + ((size_t)(b0 * NH + h) * HD + d) * SEQ + s0, tmp, 8);
      } else {
        const float sc = (mode == 0) ? SC_LOG2E_8 : 1.0f;
        uint16_t* o = (mode == 0) ? q_ws : k_ws;
#pragma unroll
        for (int j = 0; j < 4; ++j)
          o[((size_t)(b0 * NH + h) * SEQ + (s0 + j)) * HD + d] =
              f2bf((acc[fm][fn][j] + bfrag[fn]) * sc);
      }
    }
  }
}

// ---------------------------------------------------------------------------
// Flash attention, swapped-QK^T 32x32 structure (m214/T12 style).
// Wave = 32 q-rows. S^T = mfma32(K, Q): lane holds P-column q=lane&31,
// 16 key-rows crow(r,hi) = (r&3)+8*(r>>2)+4*hi per 32-key chunk.
// Softmax: in-lane trees + one permlane32_swap. P stays in registers:
// cvt_pk + permlane32_swap builds each PV B-fragment. O^T = mfma32(V^T, P^T).
// Scores pre-scaled by log2e/8 -> exp2. No LDS, no __syncthreads.
// ---------------------------------------------------------------------------
__global__ __launch_bounds__(256) void k_attn(
    const uint16_t* __restrict__ q_ws, const uint16_t* __restrict__ k_ws,
    const uint16_t* __restrict__ v_ws, const float* __restrict__ mask,
    float* __restrict__ out) {
  const int tid = threadIdx.x, lane = tid & 63, w = tid >> 6;
  const int bh = blockIdx.y;
  const int b  = bh >> 4;
  const int h  = bh & 15;
  const int q0 = blockIdx.x * 128 + w * 32;
  const int ql = lane & 31;          // this lane's q within the wave tile
  const int hi = lane >> 5;          // k-group half

  const char* kb = (const char*)k_ws;
  const char* vb = (const char*)v_ws;
  const float* mrow = mask + b * SEQ;

  // Q B-fragments: col q = ql, k(d) = s*16 + hi*8 + {0..7}
  bf16x8 qB[4];
  {
    const char* qrow = (const char*)q_ws + ((size_t)bh * SEQ + q0 + ql) * (HD * 2);
#pragma unroll
    for (int s = 0; s < 4; ++s)
      qB[s] = *(const bf16x8*)(qrow + s * 32 + hi * 16);
  }

  const f32x16 zero16 = {0.f};
  f32x16 Oacc[2];
  Oacc[0] = zero16; Oacc[1] = zero16;
  float mrun = -1e30f, lpart = 0.f;

  for (int kt = 0; kt < 32; ++kt) {
    // ---- V^T A-fragments issued early (consumed by PV at the end) ----
    bf16x8 vA[2][4];
#pragma unroll
    for (int dt = 0; dt < 2; ++dt) {
      const char* vrow = vb + ((size_t)bh * HD + dt * 32 + ql) * (SEQ * 2) + kt * 128 + hi * 16;
#pragma unroll
      for (int ks = 0; ks < 4; ++ks)
        vA[dt][ks] = *(const bf16x8*)(vrow + ks * 32);
    }

    // ---- QK^T: two 32-key chunks, S^T[key][q] ----
    f32x16 P0 = zero16, P1 = zero16;
    {
      const char* krow = kb + ((size_t)bh * SEQ + kt * 64 + ql) * 128 + hi * 16;
#pragma unroll
      for (int s = 0; s < 4; ++s) {
        bf16x8 ka = *(const bf16x8*)(krow + s * 32);
        P0 = __builtin_amdgcn_mfma_f32_32x32x16_bf16(ka, qB[s], P0, 0, 0, 0);
      }
#pragma unroll
      for (int s = 0; s < 4; ++s) {
        bf16x8 ka = *(const bf16x8*)(krow + 32 * 128 + s * 32);
        P1 = __builtin_amdgcn_mfma_f32_32x32x16_bf16(ka, qB[s], P1, 0, 0, 0);
      }
    }

    // ---- mask add: S^T[key][q] += mask[key]*SC  (key = crow(r,hi)) ----
#pragma unroll
    for (int g = 0; g < 4; ++g) {
      f32x4 m0 = *(const f32x4*)(mrow + kt * 64 + g * 8 + 4 * hi);
      f32x4 m1 = *(const f32x4*)(mrow + kt * 64 + 32 + g * 8 + 4 * hi);
#pragma unroll
      for (int t = 0; t < 4; ++t) {
        P0[g * 4 + t] += m0[t] * SC_LOG2E_8;
        P1[g * 4 + t] += m1[t] * SC_LOG2E_8;
      }
    }

    // ---- per-lane max tree over 32 values, then cross-half swap ----
    float t16[16];
#pragma unroll
    for (int r = 0; r < 16; ++r) t16[r] = fmaxf(P0[r], P1[r]);
#pragma unroll
    for (int s2 = 8; s2 > 0; s2 >>= 1)
#pragma unroll
      for (int r = 0; r < 16; ++r)
        if (r < s2) t16[r] = fmaxf(t16[r], t16[r + s2]);
    float pmax = fmaxf(t16[0], xhalf32(t16[0], lane));

    // ---- defer-max rescale (THR=8 in log2 domain) ----
    if (__any(pmax > mrun + 8.f)) {
      const float mnew = fmaxf(mrun, pmax);
      const float esc  = exp2_fast(mrun - mnew);
      mrun = mnew;
      lpart *= esc;
#pragma unroll
      for (int r = 0; r < 16; ++r) { Oacc[0][r] *= esc; Oacc[1][r] *= esc; }
    }

    // ---- exp2 + partial row-sum (in-lane) ----
    float s0 = 0.f, s1 = 0.f, s2a = 0.f, s3 = 0.f;
#pragma unroll
    for (int r = 0; r < 16; r += 4) {
      P0[r]     = exp2_fast(P0[r]     - mrun);  s0 += P0[r];
      P0[r + 1] = exp2_fast(P0[r + 1] - mrun);  s1 += P0[r + 1];
      P0[r + 2] = exp2_fast(P0[r + 2] - mrun);  s2a += P0[r + 2];
      P0[r + 3] = exp2_fast(P0[r + 3] - mrun);  s3 += P0[r + 3];
      P1[r]     = exp2_fast(P1[r]     - mrun);  s0 += P1[r];
      P1[r + 1] = exp2_fast(P1[r + 1] - mrun);  s1 += P1[r + 1];
      P1[r + 2] = exp2_fast(P1[r + 2] - mrun);  s2a += P1[r + 2];
      P1[r + 3] = exp2_fast(P1[r + 3] - mrun);  s3 += P1[r + 3];
    }
    lpart += (s0 + s1) + (s2a + s3);

    // ---- pack P^T into PV B-fragments: cvt_pk + permlane32_swap ----
    // swap(lowWord, highWord): r[0] = word for low k-slot (lo lanes keep own,
    // hi lanes get partner's highWord); r[1] = word for high k-slot.
    bf16x8 pb[4];
#pragma unroll
    for (int ks = 0; ks < 4; ++ks) {
      const int o = (ks & 1) * 8;
      uint32_t w0, w1, w2, w3;
      if (ks < 2) {
        w0 = pkbf(P0[o + 0], P0[o + 1]);
        w1 = pkbf(P0[o + 2], P0[o + 3]);
        w2 = pkbf(P0[o + 4], P0[o + 5]);
        w3 = pkbf(P0[o + 6], P0[o + 7]);
      } else {
        w0 = pkbf(P1[o + 0], P1[o + 1]);
        w1 = pkbf(P1[o + 2], P1[o + 3]);
        w2 = pkbf(P1[o + 4], P1[o + 5]);
        w3 = pkbf(P1[o + 6], P1[o + 7]);
      }
      uint32x2 r02 = plswap(w0, w2);   // r02[0]: keys {0,1}/{8,9}, r02[1]: {4,5}/{12,13}
      uint32x2 r13 = plswap(w1, w3);   // r13[0]: keys {2,3}/{10,11}, r13[1]: {6,7}/{14,15}
      uint32_t wv[4] = {r02[0], r13[0], r02[1], r13[1]};
      __builtin_memcpy(&pb[ks], wv, 16);
    }

    // ---- PV: O^T[d][q] += V^T[d][k] * P^T[k][q] ----
#pragma unroll
    for (int ks = 0; ks < 4; ++ks) {
      Oacc[0] = __builtin_amdgcn_mfma_f32_32x32x16_bf16(vA[0][ks], pb[ks], Oacc[0], 0, 0, 0);
      Oacc[1] = __builtin_amdgcn_mfma_f32_32x32x16_bf16(vA[1][ks], pb[ks], Oacc[1], 0, 0, 0);
    }
  }

  // ---- epilogue: l = own + partner; normalize; write out[b][q][h*64+d] ----
  const float ltot = lpart + xhalf32(lpart, lane);
  const float linv = 1.f / ltot;
  float* orow = out + ((size_t)(b * SEQ) + q0 + ql) * HIDDEN + h * HD;
#pragma unroll
  for (int dt = 0; dt < 2; ++dt)
#pragma unroll
    for (int g = 0; g < 4; ++g) {
      f32x4 o;
#pragma unroll
      for (int t = 0; t < 4; ++t) o[t] = Oacc[dt][g * 4 + t] * linv;
      *(f32x4*)(orow + dt * 32 + g * 8 + 4 * hi) = o;
    }
}

// ---------------------------------------------------------------------------
extern "C" void kernel_launch(void* const* d_in, const int* in_sizes, int n_in,
                              void* d_out, int out_size, void* d_ws, size_t ws_size,
                              hipStream_t stream) {
  (void)in_sizes; (void)n_in; (void)out_size; (void)ws_size;
  const float* Q    = (const float*)d_in[0];
  const float* K    = (const float*)d_in[1];
  const float* V    = (const float*)d_in[2];
  const float* mask = (const float*)d_in[3];
  const float* Wq   = (const float*)d_in[4];
  const float* bq   = (const float*)d_in[5];
  const float* Wk   = (const float*)d_in[6];
  const float* bk   = (const float*)d_in[7];
  const float* Wv   = (const float*)d_in[8];
  const float* bv   = (const float*)d_in[9];

  uint16_t* ws   = (uint16_t*)d_ws;
  uint16_t* wt_q = ws;
  uint16_t* wt_k = wt_q + HIDDEN * HIDDEN;
  uint16_t* wt_v = wt_k + HIDDEN * HIDDEN;
  const size_t qkv = (size_t)2 * SEQ * HIDDEN;
  uint16_t* Qb   = wt_v + HIDDEN * HIDDEN;
  uint16_t* Kb   = Qb + qkv;
  uint16_t* Vb   = Kb + qkv;
  uint16_t* q_ws = Vb + qkv;
  uint16_t* k_ws = q_ws + qkv;
  uint16_t* v_ws = k_ws + qkv;

  k_cvt<<<dim3(2048, 3), 256, 0, stream>>>(Q, K, V, Qb, Kb, Vb);
  k_transpose<<<dim3(256, 3), 256, 0, stream>>>(Wq, Wk, Wv, wt_q, wt_k, wt_v);
  k_qkv_gemm<<<dim3(HIDDEN / 128, (2 * SEQ) / 128, 3), 256, 0, stream>>>(
      Qb, Kb, Vb, wt_q, wt_k, wt_v, bq, bk, bv, q_ws, k_ws, v_ws);
  k_attn<<<dim3(SEQ / 128, 2 * NH), 256, 0, stream>>>(q_ws, k_ws, v_ws, mask,
                                                      (float*)d_out);
}